// Round 4
// baseline (66.486 us; speedup 1.0000x reference)
//
#include <hip/hip_runtime.h>

typedef _Float16 half8 __attribute__((ext_vector_type(8)));
typedef _Float16 half4v __attribute__((ext_vector_type(4)));
typedef float f32x16 __attribute__((ext_vector_type(16)));

#define XS 33792                 // x-tile: 4*66*128 B
#define SLOT 12288               // ring slot: 3 l * {ks0cc,ks1cc} * 2 nt * 1KB
#define LDS_TOTAL (XS + 2 * SLOT) // 58368

// async global->LDS, 16B per lane (dest = wave-uniform base + lane*16)
__device__ __forceinline__ void stage16(const void* g, const void* l) {
  __builtin_amdgcn_global_load_lds(
      (const __attribute__((address_space(1))) unsigned int*)(unsigned long long)g,
      (__attribute__((address_space(3))) unsigned int*)(unsigned int)(unsigned long long)l,
      16, 0, 0);
}

// ---------------------------------------------------------------------------
// Pre-pack W [55,64,64] f32 -> f16 MFMA B-fragments, frag order [cc][l][nt]
// (cc-major). frag f = (cc*54 + l)*2 + nt; elem e = lane*8 + v;
// value = W[l, cc*16 + (lane>>5)*8 + v, nt*32 + (lane&31)].
// Bias row (l=54) folded to f32[64] appended at Bp+221184.
// ---------------------------------------------------------------------------
__global__ __launch_bounds__(256)
void prepack_kernel(const float* __restrict__ W, _Float16* __restrict__ Bp) {
  const int idx = blockIdx.x * 256 + threadIdx.x;
  if (idx < 221184) {                    // 432 frags * 512 elems
    const int v   = idx & 7;
    const int lam = (idx >> 3) & 63;
    const int f   = idx >> 9;
    const int nt  = f & 1;
    const int lr  = f >> 1;
    const int l   = lr % 54;
    const int cc  = lr / 54;
    const int c   = cc * 16 + (lam >> 5) * 8 + v;
    const int o   = nt * 32 + (lam & 31);
    Bp[idx] = (_Float16)W[(l * 64 + c) * 64 + o];
  } else if (idx < 221184 + 64) {
    const int o = idx - 221184;
    float s = 0.f;
    for (int c = 0; c < 64; ++c) s += W[(54 * 64 + c) * 64 + o];
    ((float*)(Bp + 221184))[o] = s;
  }
}

// ---------------------------------------------------------------------------
// Block = 256 thr = 4 waves = 2 image rows (128 pixels). Wave = (nt, ks):
// M=128 (4 m-tiles of 32), N=32 (nt half), K-half = 2 ch-chunks x 54 l
// (cc-major: one chunk's 36 tap-regs live at a time). B streamed from L2 via
// global_load_lds into a 2-slot ring; counted vmcnt(3); 36 coarse phases of
// 12 MFMAs/wave. ks-split reduced via LDS overlay at the end.
// ---------------------------------------------------------------------------
__global__ __launch_bounds__(256, 2)
void qconv_kernel(const float* __restrict__ x, const _Float16* __restrict__ Bp,
                  float* __restrict__ out) {
  constexpr int IU[45] = {0,0,0,0,0,0,0,0,0, 1,1,1,1,1,1,1,1, 2,2,2,2,2,2,2,
                          3,3,3,3,3,3, 4,4,4,4,4, 5,5,5,5, 6,6,6, 7,7, 8};
  constexpr int JU[45] = {0,1,2,3,4,5,6,7,8, 1,2,3,4,5,6,7,8, 2,3,4,5,6,7,8,
                          3,4,5,6,7,8, 4,5,6,7,8, 5,6,7,8, 6,7,8, 7,8, 8};

  const int tid  = threadIdx.x;
  const int wave = tid >> 6;
  const int lane = tid & 63;
  const int nt   = wave & 1;
  const int ks   = wave >> 1;
  const int b    = blockIdx.x >> 5;
  const int h0   = (blockIdx.x & 31) * 2;

  __shared__ __align__(16) unsigned char smem[LDS_TOTAL];
  const char* BpB = (const char*)Bp;

  // ---- prologue: stage ring slots 0,1 (phases 0,1 of half 0) -------------
#pragma unroll
  for (int q = 0; q < 2; ++q) {
#pragma unroll
    for (int g = 0; g < 3; ++g) {
      const int off = g * 4096 + wave * 1024;   // dest offset within slot
      const int isB = off >= 6144;              // second ks-group's 6KB
      const int rel = off - (isB ? 6144 : 0);
      stage16(BpB + (size_t)((isB * 2) * 54 + q * 3) * 2048 + rel + lane * 16,
              smem + XS + q * SLOT + off);
    }
  }

  // ---- x tile: rows h0-1..h0+2 (4) x 66 cols x 64 ch, f16, XOR-swizzled --
  for (int idx = tid; idx < 4 * 66 * 16; idx += 256) {
    const int row = idx / (66 * 16);
    const int rem = idx - row * (66 * 16);
    const int col = rem >> 4;
    const int cg  = rem & 15;
    const int hs  = h0 - 1 + row;
    const int w   = col - 1;
    float4 v = make_float4(0.f, 0.f, 0.f, 0.f);
    if ((unsigned)hs < 64u && (unsigned)w < 64u)
      v = *(const float4*)(x + ((((size_t)b * 64 + hs) * 64 + w) * 64 + cg * 4));
    half4v hv;
    hv[0] = (_Float16)v.x; hv[1] = (_Float16)v.y;
    hv[2] = (_Float16)v.z; hv[3] = (_Float16)v.w;
    const int addr = (row * 8448 + col * 128 + cg * 8) ^ ((col & 7) << 4);
    *(half4v*)(smem + addr) = hv;
  }
  __syncthreads();

  f32x16 acc[4] = {};                // 4 m-tiles x 16 f32
  const int colA = lane & 31;
  const int kg   = lane >> 5;

  for (int h = 0; h < 2; ++h) {      // cc-major: one chunk's taps at a time
    const int cc    = ks * 2 + h;
    const int cbyte = cc * 32 + kg * 16;

    half8 tap[4][9];                 // 144 VGPRs
#pragma unroll
    for (int mt = 0; mt < 4; ++mt)
#pragma unroll
      for (int t = 0; t < 9; ++t) {
        const int ce = (mt & 1) * 32 + colA + (t % 3);
        const int a  = (((mt >> 1) + t / 3) * 8448 + ce * 128 + cbyte)
                       ^ ((ce & 7) << 4);
        tap[mt][t] = *(const half8*)(smem + a);
      }

#pragma unroll
    for (int pl = 0; pl < 18; ++pl) {
      asm volatile("s_waitcnt vmcnt(3)" ::: "memory");  // this slot landed
      __builtin_amdgcn_s_barrier();
      const unsigned sb = XS + (pl & 1) * SLOT + ks * 6144 + nt * 1024
                          + lane * 16;
      const half8 bf0 = *(const half8*)(smem + sb);
      const half8 bf1 = *(const half8*)(smem + sb + 2048);
      const half8 bf2 = *(const half8*)(smem + sb + 4096);
      __builtin_amdgcn_s_setprio(1);
#pragma unroll
      for (int j = 0; j < 3; ++j) {
        const int l = pl * 3 + j;
        const half8 bf = (j == 0) ? bf0 : ((j == 1) ? bf1 : bf2);
#pragma unroll
        for (int mt = 0; mt < 4; ++mt) {
          half8 a;
          if (l < 45) a = tap[mt][IU[l]] * tap[mt][JU[l]];  // v_pk_mul_f16
          else        a = tap[mt][l - 45];
          acc[mt] = __builtin_amdgcn_mfma_f32_32x32x16_f16(a, bf, acc[mt],
                                                           0, 0, 0);
        }
      }
      __builtin_amdgcn_s_setprio(0);
      asm volatile("s_waitcnt lgkmcnt(0)" ::: "memory");   // my reads retired
      __builtin_amdgcn_s_barrier();                        // slot free
      // stage global phase Q = (h*18 + pl + 2) % 36 into the freed slot
      const int hq  = (pl <= 15) ? h : 1 - h;
      const int lq0 = ((pl <= 15) ? (pl + 2) : (pl - 16)) * 3;
#pragma unroll
      for (int g = 0; g < 3; ++g) {
        const int off = g * 4096 + wave * 1024;
        const int isB = off >= 6144;
        const int rel = off - (isB ? 6144 : 0);
        stage16(BpB + (size_t)((isB * 2 + hq) * 54 + lq0) * 2048 + rel
                    + lane * 16,
                smem + XS + (pl & 1) * SLOT + off);
      }
    }
  }

  asm volatile("s_waitcnt vmcnt(0)" ::: "memory");  // drain wrap-stages
  __syncthreads();

  // ---- ks-split reduction (red overlays x-tile region, 32KB) -------------
  float* red = (float*)smem;        // [nt][mt][32 rows][32 cols]
  const int colD = lane & 31;
  const int rg   = lane >> 5;

  if (ks == 1) {
#pragma unroll
    for (int mt = 0; mt < 4; ++mt)
#pragma unroll
      for (int g = 0; g < 16; ++g) {
        const int rowD = (g & 3) + 8 * (g >> 2) + 4 * rg;
        red[((nt * 4 + mt) * 32 + rowD) * 32 + colD] = acc[mt][g];
      }
  }
  __syncthreads();
  if (ks == 0) {
    const float bias = ((const float*)(Bp + 221184))[nt * 32 + colD];
#pragma unroll
    for (int mt = 0; mt < 4; ++mt) {
      float* op = out + (((size_t)b * 64 + h0 + (mt >> 1)) * 64
                         + (mt & 1) * 32) * 64 + nt * 32 + colD;
#pragma unroll
      for (int g = 0; g < 16; ++g) {
        const int rowD = (g & 3) + 8 * (g >> 2) + 4 * rg;
        op[(size_t)rowD * 64] =
            acc[mt][g] + red[((nt * 4 + mt) * 32 + rowD) * 32 + colD] + bias;
      }
    }
  }
}

extern "C" void kernel_launch(void* const* d_in, const int* in_sizes, int n_in,
                              void* d_out, int out_size, void* d_ws, size_t ws_size,
                              hipStream_t stream) {
  const float* x = (const float*)d_in[0];
  const float* W = (const float*)d_in[1];
  float* out     = (float*)d_out;
  _Float16* Bp   = (_Float16*)d_ws;   // 442,368 B frags + 256 B bias

  prepack_kernel<<<dim3((221248 + 255) / 256), dim3(256), 0, stream>>>(W, Bp);
  qconv_kernel<<<dim3(512), dim3(256), 0, stream>>>(x, Bp, out);
}

// Round 5
// 44.794 us; speedup vs baseline: 1.4843x; 1.4843x over previous
//
#include <hip/hip_runtime.h>

typedef _Float16 half8 __attribute__((ext_vector_type(8)));
typedef _Float16 half4v __attribute__((ext_vector_type(4)));
typedef float f32x16 __attribute__((ext_vector_type(16)));

#define BOFF 0                   // B-slice: 108 frags * 1KB = 110592 B
#define XOFF 110592              // x-tile: 10 rows * 66 cols * 64 B = 42240 B
#define LDS_TOTAL 152832

// async global->LDS, 16B/lane; dest is the WAVE-UNIFORM base (HW adds lane*16)
__device__ __forceinline__ void stage16(const void* g, const void* l) {
  __builtin_amdgcn_global_load_lds(
      (const __attribute__((address_space(1))) unsigned int*)(unsigned long long)g,
      (__attribute__((address_space(3))) unsigned int*)(unsigned int)(unsigned long long)l,
      16, 0, 0);
}

// ---------------------------------------------------------------------------
// Pre-pack W [55,64,64] f32 -> f16 MFMA B-fragments, order [nt][ks][cc][l]:
// frag f = ((nt*2+ks)*2 + cc)*54 + l ; elem e = lane*8 + v ;
// value = W[l, (ks*2+cc)*16 + (lane>>5)*8 + v, nt*32 + (lane&31)].
// Bias row (l=54) folded to f32[64] at byte offset 442368.
// ---------------------------------------------------------------------------
__global__ __launch_bounds__(256)
void prepack_kernel(const float* __restrict__ W, _Float16* __restrict__ Bp) {
  const int idx = blockIdx.x * 256 + threadIdx.x;
  if (idx < 221184) {                    // 432 frags * 512 elems
    const int v   = idx & 7;
    const int lam = (idx >> 3) & 63;
    const int f   = idx >> 9;
    const int l   = f % 54;
    const int r   = f / 54;
    const int cc  = r & 1;
    const int ks  = (r >> 1) & 1;
    const int nt  = (r >> 2) & 1;
    const int c   = (ks * 2 + cc) * 16 + (lam >> 5) * 8 + v;
    const int o   = nt * 32 + (lam & 31);
    Bp[idx] = (_Float16)W[(l * 64 + c) * 64 + o];
  } else if (idx < 221184 + 64) {
    const int o = idx - 221184;
    float s = 0.f;
    for (int c = 0; c < 64; ++c) s += W[(54 * 64 + c) * 64 + o];
    ((float*)(Bp + 221184))[o] = s;
  }
}

// ---------------------------------------------------------------------------
// Persistent-B kernel. Grid 256 (= 1 block/CU): 128 pixel-groups (8 rows of
// one image) x 2 nt. Block = 4 waves; wave = 2 rows = 4 m-tiles of 32, N=32.
// B-slice (nt,ks) = 108KB resident in LDS; two ks-rounds in time, acc in regs
// across rounds (no reduction). Main loop has NO barriers: ds_read + MFMA
// with depth-2 fragment prefetch only.
// ---------------------------------------------------------------------------
__global__ __launch_bounds__(256, 1)
void qconv_kernel(const float* __restrict__ x, const _Float16* __restrict__ Bp,
                  float* __restrict__ out) {
  constexpr int IU[45] = {0,0,0,0,0,0,0,0,0, 1,1,1,1,1,1,1,1, 2,2,2,2,2,2,2,
                          3,3,3,3,3,3, 4,4,4,4,4, 5,5,5,5, 6,6,6, 7,7, 8};
  constexpr int JU[45] = {0,1,2,3,4,5,6,7,8, 1,2,3,4,5,6,7,8, 2,3,4,5,6,7,8,
                          3,4,5,6,7,8, 4,5,6,7,8, 5,6,7,8, 6,7,8, 7,8, 8};

  const int tid  = threadIdx.x;
  const int wave = tid >> 6;          // mh: rows {2*wave, 2*wave+1} of group
  const int lane = tid & 63;
  const int colA = lane & 31;
  const int kg   = lane >> 5;

  // XCD-aware logical remap: blocks on one XCD cover 2 images (x L2-fit)
  const int phys = blockIdx.x;        // 0..255, %8 round-robins XCDs
  const int xcd  = phys & 7;
  const int slot = phys >> 3;         // 0..31
  const int g    = xcd * 16 + (slot >> 1);   // pixel-group 0..127
  const int nt   = slot & 1;
  const int b    = g >> 3;
  const int r0   = (g & 7) * 8;

  __shared__ __align__(16) unsigned char smem[LDS_TOTAL];
  const char* BpB = (const char*)Bp;

  f32x16 acc[4] = {};                 // persists across both ks-rounds

  for (int ks = 0; ks < 2; ++ks) {
    __syncthreads();                  // everyone done reading previous B + x

    // ---- stage B-slice (108 frags) async into LDS: 27 per wave ----------
    const size_t bSrc = (size_t)(nt * 2 + ks) * 110592;
    for (int q = 0; q < 27; ++q) {
      const int f = wave * 27 + q;
      stage16(BpB + bSrc + (size_t)f * 1024 + lane * 16,
              (char*)smem + BOFF + f * 1024);      // uniform base, HW +lane*16
    }

    // ---- stage x-tile: 10 rows x 66 cols x 32 ch (this ks-half), f16 -----
    for (int idx = tid; idx < 5280; idx += 256) {
      const int row = idx / 528;
      const int rem = idx - row * 528;
      const int col = rem >> 3;
      const int gq  = rem & 7;
      const int hh  = r0 - 1 + row;
      const int ww  = col - 1;
      float4 v = make_float4(0.f, 0.f, 0.f, 0.f);
      if ((unsigned)hh < 64u && (unsigned)ww < 64u)
        v = *(const float4*)(x + ((((size_t)b * 64 + hh) * 64 + ww) * 64
                                  + ks * 32 + gq * 4));
      half4v hv;
      hv[0] = (_Float16)v.x; hv[1] = (_Float16)v.y;
      hv[2] = (_Float16)v.z; hv[3] = (_Float16)v.w;
      const int addr = XOFF + ((row * 4224 + col * 64 + gq * 8)
                               ^ (((col >> 1) & 3) << 4));
      *(half4v*)(smem + addr) = hv;
    }

    asm volatile("s_waitcnt vmcnt(0)" ::: "memory");   // B landed
    __syncthreads();                                    // x writes visible

    // ---- barrier-free compute: 2 cc-chunks x 54 l, 4 MFMA each ----------
#pragma unroll
    for (int cc = 0; cc < 2; ++cc) {
      half8 tap[4][9];                // 144 VGPRs (budget 512 at 1 blk/CU)
#pragma unroll
      for (int mt = 0; mt < 4; ++mt)
#pragma unroll
        for (int t = 0; t < 9; ++t) {
          const int xrow = 2 * wave + (mt >> 1) + t / 3;
          const int ce   = (mt & 1) * 32 + colA + (t % 3);
          const int a = XOFF + ((xrow * 4224 + ce * 64 + cc * 32 + kg * 16)
                                ^ (((ce >> 1) & 3) << 4));
          tap[mt][t] = *(const half8*)(smem + a);
        }

      const unsigned fb = BOFF + cc * 54 * 1024 + lane * 16;
      half8 pfA = *(const half8*)(smem + fb);
      half8 pfB = *(const half8*)(smem + fb + 1024);
#pragma unroll
      for (int l = 0; l < 54; ++l) {
        const half8 bf = (l & 1) ? pfB : pfA;
        if (l + 2 < 54) {             // compile-time after unroll
          if (l & 1) pfB = *(const half8*)(smem + fb + (l + 2) * 1024);
          else       pfA = *(const half8*)(smem + fb + (l + 2) * 1024);
        }
#pragma unroll
        for (int mt = 0; mt < 4; ++mt) {
          half8 a;
          if (l < 45) a = tap[mt][IU[l]] * tap[mt][JU[l]];  // v_pk_mul_f16
          else        a = tap[mt][l - 45];
          acc[mt] = __builtin_amdgcn_mfma_f32_32x32x16_f16(a, bf, acc[mt],
                                                           0, 0, 0);
        }
      }
    }
  }

  // ---- epilogue: bias + plain coalesced stores ---------------------------
  const float bias = ((const float*)(BpB + 442368))[nt * 32 + colA];
#pragma unroll
  for (int mt = 0; mt < 4; ++mt) {
    float* op = out + (((size_t)b * 64 + r0 + 2 * wave + (mt >> 1)) * 64
                       + (mt & 1) * 32) * 64 + nt * 32 + colA;
#pragma unroll
    for (int gi = 0; gi < 16; ++gi) {
      const int rowD = (gi & 3) + 8 * (gi >> 2) + 4 * kg;  // pixel within mt
      op[(size_t)rowD * 64] = acc[mt][gi] + bias;
    }
  }
}

extern "C" void kernel_launch(void* const* d_in, const int* in_sizes, int n_in,
                              void* d_out, int out_size, void* d_ws, size_t ws_size,
                              hipStream_t stream) {
  const float* x = (const float*)d_in[0];
  const float* W = (const float*)d_in[1];
  float* out     = (float*)d_out;
  _Float16* Bp   = (_Float16*)d_ws;   // 442368 B frags + 256 B bias

  prepack_kernel<<<dim3((221248 + 255) / 256), dim3(256), 0, stream>>>(W, Bp);
  qconv_kernel<<<dim3(256), dim3(256), 0, stream>>>(x, Bp, out);
}

// Round 6
// 40.611 us; speedup vs baseline: 1.6371x; 1.1030x over previous
//
#include <hip/hip_runtime.h>

typedef _Float16 half8 __attribute__((ext_vector_type(8)));
typedef _Float16 half4v __attribute__((ext_vector_type(4)));
typedef float f32x16 __attribute__((ext_vector_type(16)));

#define BOFF 0                   // B-slice: 108 frags * 1KB = 110592 B
#define XOFF 110592              // x-tile: 10 rows * 66 cols * 32ch f16 = 42240 B
#define LDS_TOTAL 152832

// async global->LDS, 16B/lane; dest is the WAVE-UNIFORM base (HW adds lane*16)
__device__ __forceinline__ void stage16(const void* g, const void* l) {
  __builtin_amdgcn_global_load_lds(
      (const __attribute__((address_space(1))) unsigned int*)(unsigned long long)g,
      (__attribute__((address_space(3))) unsigned int*)(unsigned int)(unsigned long long)l,
      16, 0, 0);
}

// ---------------------------------------------------------------------------
// Pre-pack W [55,64,64] f32 -> f16 MFMA B-fragments, order [nt][ks][cc][l]:
// frag f = ((nt*2+ks)*2 + cc)*54 + l ; elem e = lane*8 + v ;
// value = W[l, (ks*2+cc)*16 + (lane>>5)*8 + v, nt*32 + (lane&31)].
// Bias row (l=54) folded to f32[64] at byte offset 442368.
// ---------------------------------------------------------------------------
__global__ __launch_bounds__(256)
void prepack_kernel(const float* __restrict__ W, _Float16* __restrict__ Bp) {
  const int idx = blockIdx.x * 256 + threadIdx.x;
  if (idx < 221184) {                    // 432 frags * 512 elems
    const int v   = idx & 7;
    const int lam = (idx >> 3) & 63;
    const int f   = idx >> 9;
    const int l   = f % 54;
    const int r   = f / 54;
    const int cc  = r & 1;
    const int ks  = (r >> 1) & 1;
    const int nt  = (r >> 2) & 1;
    const int c   = (ks * 2 + cc) * 16 + (lam >> 5) * 8 + v;
    const int o   = nt * 32 + (lam & 31);
    Bp[idx] = (_Float16)W[(l * 64 + c) * 64 + o];
  } else if (idx < 221184 + 64) {
    const int o = idx - 221184;
    float s = 0.f;
    for (int c = 0; c < 64; ++c) s += W[(54 * 64 + c) * 64 + o];
    ((float*)(Bp + 221184))[o] = s;
  }
}

// ---------------------------------------------------------------------------
// Persistent-B kernel, 8 waves (2/SIMD). Grid 256 = 1 block/CU: 128 pixel-
// groups (8 rows of one image) x 2 nt. Block = 512 thr = 8 waves; wave w owns
// image row r0+w (64 px = 2 m-tiles of 32), N=32 (nt). B-slice (nt,ks) =
// 108 KB resident in LDS; two temporal ks-rounds, acc held in regs across
// rounds. Main loop barrier-free: ds_read + MFMA with depth-2 frag prefetch.
// ---------------------------------------------------------------------------
__global__ __launch_bounds__(512, 2)
void qconv_kernel(const float* __restrict__ x, const _Float16* __restrict__ Bp,
                  float* __restrict__ out) {
  constexpr int IU[45] = {0,0,0,0,0,0,0,0,0, 1,1,1,1,1,1,1,1, 2,2,2,2,2,2,2,
                          3,3,3,3,3,3, 4,4,4,4,4, 5,5,5,5, 6,6,6, 7,7, 8};
  constexpr int JU[45] = {0,1,2,3,4,5,6,7,8, 1,2,3,4,5,6,7,8, 2,3,4,5,6,7,8,
                          3,4,5,6,7,8, 4,5,6,7,8, 5,6,7,8, 6,7,8, 7,8, 8};

  const int tid  = threadIdx.x;
  const int wave = tid >> 6;          // 0..7 -> image row r0+wave
  const int lane = tid & 63;
  const int colA = lane & 31;
  const int kg   = lane >> 5;

  // XCD-aware logical remap (grid 256 = 32 blocks per XCD)
  const int phys = blockIdx.x;
  const int xcd  = phys & 7;
  const int slot = phys >> 3;              // 0..31
  const int g    = xcd * 16 + (slot >> 1); // pixel-group 0..127
  const int nt   = slot & 1;
  const int b    = g >> 3;
  const int r0   = (g & 7) * 8;

  __shared__ __align__(16) unsigned char smem[LDS_TOTAL];
  const char* BpB = (const char*)Bp;

  f32x16 acc[2] = {};                 // persists across both ks-rounds

  for (int ks = 0; ks < 2; ++ks) {
    __syncthreads();                  // everyone done reading previous B + x

    // ---- stage B-slice (108 frags) async: 13-14 per wave ---------------
    const size_t bSrc = (size_t)(nt * 2 + ks) * 110592;
    for (int f = wave; f < 108; f += 8)
      stage16(BpB + bSrc + (size_t)f * 1024 + lane * 16,
              (char*)smem + BOFF + f * 1024);   // uniform base, HW +lane*16

    // ---- stage x-tile: 10 rows x 66 cols x 32 ch (this ks-half), f16 ----
    for (int idx = tid; idx < 5280; idx += 512) {
      const int row = idx / 528;
      const int rem = idx - row * 528;
      const int col = rem >> 3;
      const int gq  = rem & 7;
      const int hh  = r0 - 1 + row;
      const int ww  = col - 1;
      float4 v = make_float4(0.f, 0.f, 0.f, 0.f);
      if ((unsigned)hh < 64u && (unsigned)ww < 64u)
        v = *(const float4*)(x + ((((size_t)b * 64 + hh) * 64 + ww) * 64
                                  + ks * 32 + gq * 4));
      half4v hv;
      hv[0] = (_Float16)v.x; hv[1] = (_Float16)v.y;
      hv[2] = (_Float16)v.z; hv[3] = (_Float16)v.w;
      const int addr = XOFF + ((row * 4224 + col * 64 + gq * 8)
                               ^ (((col >> 1) & 3) << 4));
      *(half4v*)(smem + addr) = hv;
    }

    asm volatile("s_waitcnt vmcnt(0)" ::: "memory");   // B landed
    __syncthreads();                                    // x writes visible

    // ---- barrier-free compute: 2 cc-chunks x 54 l, 2 MFMA each ----------
#pragma unroll
    for (int cc = 0; cc < 2; ++cc) {
      half8 tap[2][9];                // 72 VGPRs
#pragma unroll
      for (int mt = 0; mt < 2; ++mt)
#pragma unroll
        for (int t = 0; t < 9; ++t) {
          const int xrow = wave + t / 3;           // tile rows wave..wave+2
          const int ce   = mt * 32 + colA + (t % 3);
          const int a = XOFF + ((xrow * 4224 + ce * 64 + cc * 32 + kg * 16)
                                ^ (((ce >> 1) & 3) << 4));
          tap[mt][t] = *(const half8*)(smem + a);
        }

      const unsigned fb = BOFF + cc * 54 * 1024 + lane * 16;
      half8 pfA = *(const half8*)(smem + fb);
      half8 pfB = *(const half8*)(smem + fb + 1024);
#pragma unroll
      for (int l = 0; l < 54; ++l) {
        const half8 bf = (l & 1) ? pfB : pfA;
        if (l + 2 < 54) {             // compile-time after unroll
          if (l & 1) pfB = *(const half8*)(smem + fb + (l + 2) * 1024);
          else       pfA = *(const half8*)(smem + fb + (l + 2) * 1024);
        }
#pragma unroll
        for (int mt = 0; mt < 2; ++mt) {
          half8 a;
          if (l < 45) a = tap[mt][IU[l]] * tap[mt][JU[l]];  // v_pk_mul_f16
          else        a = tap[mt][l - 45];
          acc[mt] = __builtin_amdgcn_mfma_f32_32x32x16_f16(a, bf, acc[mt],
                                                           0, 0, 0);
        }
      }
    }
  }

  // ---- epilogue: bias + coalesced stores ---------------------------------
  const float bias = ((const float*)(BpB + 442368))[nt * 32 + colA];
#pragma unroll
  for (int mt = 0; mt < 2; ++mt) {
    float* op = out + (((size_t)b * 64 + r0 + wave) * 64 + mt * 32) * 64
                    + nt * 32 + colA;
#pragma unroll
    for (int gi = 0; gi < 16; ++gi) {
      const int rowD = (gi & 3) + 8 * (gi >> 2) + 4 * kg;  // pixel within mt
      op[(size_t)rowD * 64] = acc[mt][gi] + bias;
    }
  }
}

extern "C" void kernel_launch(void* const* d_in, const int* in_sizes, int n_in,
                              void* d_out, int out_size, void* d_ws, size_t ws_size,
                              hipStream_t stream) {
  const float* x = (const float*)d_in[0];
  const float* W = (const float*)d_in[1];
  float* out     = (float*)d_out;
  _Float16* Bp   = (_Float16*)d_ws;   // 442368 B frags + 256 B bias

  prepack_kernel<<<dim3((221248 + 255) / 256), dim3(256), 0, stream>>>(W, Bp);
  qconv_kernel<<<dim3(256), dim3(512), 0, stream>>>(x, Bp, out);
}